// Round 20
// baseline (117.648 us; speedup 1.0000x reference)
//
#include <hip/hip_runtime.h>

#define NNODES 100000
#define NEDGES 625000
#define DIM 128
#define NTILES 782            // ceil(100000/128)
#define FBLK 1221             // ceil(625000/512) fill-role blocks
#define BCAP 64               // bucket capacity (r14-proven; P(deg>64)~0)

typedef short short8 __attribute__((ext_vector_type(8)));
typedef unsigned short ushort8 __attribute__((ext_vector_type(8)));
typedef float f32x4  __attribute__((ext_vector_type(4)));

__device__ __forceinline__ unsigned short f2bf(float f) {
    unsigned u = __float_as_uint(f);
    u += 0x7FFFu + ((u >> 16) & 1u);      // RNE
    return (unsigned short)(u >> 16);
}
__device__ __forceinline__ float bf_lo(unsigned u) { return __uint_as_float(u << 16); }
__device__ __forceinline__ float bf_hi(unsigned u) { return __uint_as_float(u & 0xFFFF0000u); }

// ===== dispatch 1: fused two-phase gemm + bucketed fill =====
// gemm role (bid < NTILES): r19 two-phase form, 32KB LDS — stage Wl-half ->
// Y, barrier, restage Wr-half -> Z. x loaded once, bf16 A-frags held in regs.
// fill role (bid >= NTILES): tail blocks stream edges; disjoint dataflow
// (ei->cnt/adjb atomics) overlaps gemm's MFMA+memory. 32KB LDS keeps the
// dispatch at the 2048-thr/CU cap (4 blocks) — r13's 64KB-LDS fusion trap
// (2 blocks/CU strangling the latency-bound role) doesn't apply.
// cnt is zeroed by a preceding 400KB memset.
template<bool ZBF>
__global__ __launch_bounds__(512, 4) void gemm_fill_kernel(
    const float* __restrict__ x,
    const float* __restrict__ Wl,
    const float* __restrict__ Wr,
    unsigned short* __restrict__ Yh,      // [NNODES][128] bf16, permuted slots
    unsigned short* __restrict__ Zh,      // [NNODES][128] bf16, permuted (ZBF)
    float* __restrict__ Z,                // = d_out, permuted fp32 (!ZBF)
    const int* __restrict__ ei,
    int* __restrict__ cnt,
    int* __restrict__ adjb)
{
    __shared__ unsigned short wfrag[16384];   // 32KB: one W-half, restaged
    const int tid = threadIdx.x;
    const int bid = blockIdx.x;

    if (bid >= NTILES) {                      // ---- fill role ----
        int e = (bid - NTILES) * 512 + tid;
        if (e < NEDGES) {
            int src = ei[e];
            int dst = ei[NEDGES + e];
            int p = atomicAdd(&cnt[dst], 1);
            if (p < BCAP) adjb[(size_t)dst * BCAP + p] = src;
        }
        return;                               // whole block exits: no barrier issue
    }

    const int wave = tid >> 6;
    const int lane = tid & 63;
    const int lrow = lane & 15;
    const int kgrp = lane >> 4;
    const int row0 = bid * 128 + wave * 16;

    // ---- load x row once; keep bf16 A-frags across both phases ----
    int arow = row0 + lrow;
    if (arow >= NNODES) arow = NNODES - 1;    // clamped rows never stored
    const float* xrow = x + (size_t)arow * DIM + kgrp * 8;
    short8 af[4];
#pragma unroll
    for (int ks = 0; ks < 4; ++ks) {
        float4 a0 = *(const float4*)(xrow + ks * 32);
        float4 a1 = *(const float4*)(xrow + ks * 32 + 4);
        af[ks][0] = (short)f2bf(a0.x); af[ks][1] = (short)f2bf(a0.y);
        af[ks][2] = (short)f2bf(a0.z); af[ks][3] = (short)f2bf(a0.w);
        af[ks][4] = (short)f2bf(a1.x); af[ks][5] = (short)f2bf(a1.y);
        af[ks][6] = (short)f2bf(a1.z); af[ks][7] = (short)f2bf(a1.w);
    }

    // ================= phase A: Wl -> Y =================
#pragma unroll
    for (int it = 0; it < 4; ++it) {          // stage 2048 chunks x 16B
        const int i  = it * 512 + tid;
        const int il = i & 63;
        const int ks = (i >> 6) & 3;
        const int ct = i >> 8;                // 0..7
        const float* wr = Wl + (size_t)(ct * 16 + (il & 15)) * DIM
                             + (ks * 4 + (il >> 4)) * 8;
        float4 w0 = *(const float4*)(wr);
        float4 w1 = *(const float4*)(wr + 4);
        ushort8 c;
        c[0] = f2bf(w0.x); c[1] = f2bf(w0.y); c[2] = f2bf(w0.z); c[3] = f2bf(w0.w);
        c[4] = f2bf(w1.x); c[5] = f2bf(w1.y); c[6] = f2bf(w1.z); c[7] = f2bf(w1.w);
        *(ushort8*)(wfrag + (size_t)i * 8) = c;
    }
    __syncthreads();

    {
        f32x4 acc[8];
#pragma unroll
        for (int i = 0; i < 8; ++i) acc[i] = (f32x4){0.f, 0.f, 0.f, 0.f};
#pragma unroll
        for (int ks = 0; ks < 4; ++ks)
#pragma unroll
            for (int ct = 0; ct < 8; ++ct) {
                short8 bf = *(const short8*)(wfrag + (size_t)((ct * 4 + ks) * 64 + lane) * 8);
                acc[ct] = __builtin_amdgcn_mfma_f32_16x16x32_bf16(af[ks], bf, acc[ct], 0, 0, 0);
            }
#pragma unroll
        for (int r = 0; r < 4; ++r) {
            const int row = row0 + kgrp * 4 + r;
            if (row < NNODES) {
                ushort8 y;
#pragma unroll
                for (int ct = 0; ct < 8; ++ct) y[ct] = f2bf(acc[ct][r]);
                *(ushort8*)(Yh + (size_t)row * DIM + lrow * 8) = y;
            }
        }
    }

    __syncthreads();   // all phase-A LDS reads done before restage

    // ================= phase B: Wr -> Z =================
#pragma unroll
    for (int it = 0; it < 4; ++it) {
        const int i  = it * 512 + tid;
        const int il = i & 63;
        const int ks = (i >> 6) & 3;
        const int ct = i >> 8;
        const float* wr = Wr + (size_t)(ct * 16 + (il & 15)) * DIM
                             + (ks * 4 + (il >> 4)) * 8;
        float4 w0 = *(const float4*)(wr);
        float4 w1 = *(const float4*)(wr + 4);
        ushort8 c;
        c[0] = f2bf(w0.x); c[1] = f2bf(w0.y); c[2] = f2bf(w0.z); c[3] = f2bf(w0.w);
        c[4] = f2bf(w1.x); c[5] = f2bf(w1.y); c[6] = f2bf(w1.z); c[7] = f2bf(w1.w);
        *(ushort8*)(wfrag + (size_t)i * 8) = c;
    }
    __syncthreads();

    {
        f32x4 acc[8];
#pragma unroll
        for (int i = 0; i < 8; ++i) acc[i] = (f32x4){0.f, 0.f, 0.f, 0.f};
#pragma unroll
        for (int ks = 0; ks < 4; ++ks)
#pragma unroll
            for (int ct = 0; ct < 8; ++ct) {
                short8 bf = *(const short8*)(wfrag + (size_t)((ct * 4 + ks) * 64 + lane) * 8);
                acc[ct] = __builtin_amdgcn_mfma_f32_16x16x32_bf16(af[ks], bf, acc[ct], 0, 0, 0);
            }
#pragma unroll
        for (int r = 0; r < 4; ++r) {
            const int row = row0 + kgrp * 4 + r;
            if (row < NNODES) {
                if (ZBF) {
                    ushort8 zz;
#pragma unroll
                    for (int ct = 0; ct < 8; ++ct) zz[ct] = f2bf(acc[ct][r]);
                    *(ushort8*)(Zh + (size_t)row * DIM + lrow * 8) = zz;
                } else {
                    float4 z0, z1;
                    z0.x = acc[0][r]; z0.y = acc[1][r]; z0.z = acc[2][r]; z0.w = acc[3][r];
                    z1.x = acc[4][r]; z1.y = acc[5][r]; z1.z = acc[6][r]; z1.w = acc[7][r];
                    *(float4*)(Z + (size_t)row * DIM + lrow * 8)     = z0;
                    *(float4*)(Z + (size_t)row * DIM + lrow * 8 + 4) = z1;
                }
            }
        }
    }
}

// ===== dispatch 2: aggregate — r18-proven form (256-thr, quarter-wave) =====
template<bool ZBF>
__global__ __launch_bounds__(256) void aggregate_kernel(
    const unsigned short* __restrict__ Yh,
    const unsigned short* __restrict__ Zh,
    const int* __restrict__ cnt,
    const int* __restrict__ adjb,
    const float* __restrict__ bias,
    float* __restrict__ out)
{
    const int tid = threadIdx.x;
    const int l16 = tid & 15;
    const int n = blockIdx.x * 16 + (tid >> 4);
    if (n >= NNODES) return;

    int deg = cnt[n];
    if (deg > BCAP) deg = BCAP;

    float bb[8], z[8];
#pragma unroll
    for (int m = 0; m < 8; ++m) bb[m] = bias[16 * m + l16];   // inverse perm
    if (ZBF) {
        uint4 zv = *(const uint4*)(Zh + (size_t)n * DIM + l16 * 8);
        z[0] = bf_lo(zv.x); z[1] = bf_hi(zv.x); z[2] = bf_lo(zv.y); z[3] = bf_hi(zv.y);
        z[4] = bf_lo(zv.z); z[5] = bf_hi(zv.z); z[6] = bf_lo(zv.w); z[7] = bf_hi(zv.w);
    } else {
        float4 z0 = *(const float4*)(out + (size_t)n * DIM + l16 * 8);
        float4 z1 = *(const float4*)(out + (size_t)n * DIM + l16 * 8 + 4);
        z[0] = z0.x; z[1] = z0.y; z[2] = z0.z; z[3] = z0.w;
        z[4] = z1.x; z[5] = z1.y; z[6] = z1.z; z[7] = z1.w;
    }

    float a[8];
#pragma unroll
    for (int m = 0; m < 8; ++m) a[m] = 0.f;

    const int* bkt = adjb + (size_t)n * BCAP;
    for (int j = 0; j < deg; j += 8) {
        const int rem = deg - j;             // >= 1, quarter-wave-uniform
        int s[8];
#pragma unroll
        for (int k = 0; k < 8; ++k) {
            int idx = j + k;
            s[k] = bkt[(idx < deg) ? idx : (deg - 1)];   // clamp: in-bucket
        }
        uint4 v[8];
#pragma unroll
        for (int k = 0; k < 8; ++k)
            v[k] = *(const uint4*)(Yh + (size_t)s[k] * DIM + l16 * 8);
#pragma unroll
        for (int k = 0; k < 8; ++k) {
            if (k < rem) {                   // predicated accumulate
                a[0] += bf_lo(v[k].x); a[1] += bf_hi(v[k].x);
                a[2] += bf_lo(v[k].y); a[3] += bf_hi(v[k].y);
                a[4] += bf_lo(v[k].z); a[5] += bf_hi(v[k].z);
                a[6] += bf_lo(v[k].w); a[7] += bf_hi(v[k].w);
            }
        }
    }

    const float invd = 1.0f / fmaxf((float)deg, 1.0f);
#pragma unroll
    for (int m = 0; m < 8; ++m)              // slot 8*l16+m -> true col 16*m+l16
        out[(size_t)n * DIM + 16 * m + l16] = fmaxf(a[m] * invd + z[m] + bb[m], 0.f);
}

extern "C" void kernel_launch(void* const* d_in, const int* in_sizes, int n_in,
                              void* d_out, int out_size, void* d_ws, size_t ws_size,
                              hipStream_t stream) {
    const float* x  = (const float*)d_in[0];
    const int*   ei = (const int*)d_in[1];   // int32 (harness converts int64)
    const float* Wl = (const float*)d_in[2];
    const float* Wr = (const float*)d_in[3];
    const float* b  = (const float*)d_in[4];
    float* out = (float*)d_out;

    // ws layout:
    //   [0,    400K) cnt   int[NNODES]
    //   [1M,  +25.6M) adjb  int[NNODES*BCAP]
    //   [27M, +25.6M) Yh    bf16[NNODES*128]  (permuted slots)
    //   [53M, +25.6M) Zh    bf16[NNODES*128]  (permuted slots, ZBF only)
    int*            cnt  = (int*)d_ws;
    int*            adjb = (int*)((char*)d_ws + (1ull << 20));
    unsigned short* Yh   = (unsigned short*)((char*)d_ws + (27ull << 20));
    unsigned short* Zh   = (unsigned short*)((char*)d_ws + (53ull << 20));

    const size_t need_zbf = (53ull << 20) + (size_t)NNODES * DIM * 2;  // ~78.6MB
    const bool zbf = (ws_size >= need_zbf);

    hipMemsetAsync(cnt, 0, NNODES * sizeof(int), stream);

    if (zbf) {
        gemm_fill_kernel<true><<<NTILES + FBLK, 512, 0, stream>>>(x, Wl, Wr, Yh, Zh, out, ei, cnt, adjb);
        aggregate_kernel<true><<<(NNODES + 15) / 16, 256, 0, stream>>>(Yh, Zh, cnt, adjb, b, out);
    } else {
        gemm_fill_kernel<false><<<NTILES + FBLK, 512, 0, stream>>>(x, Wl, Wr, Yh, Zh, out, ei, cnt, adjb);
        aggregate_kernel<false><<<(NNODES + 15) / 16, 256, 0, stream>>>(Yh, Zh, cnt, adjb, b, out);
    }
}

// Round 21
// 98.728 us; speedup vs baseline: 1.1916x; 1.1916x over previous
//
#include <hip/hip_runtime.h>

#define NNODES 100000
#define NEDGES 625000
#define DIM 128
#define NTILES 782            // ceil(100000/128)
#define ZBLK 98               // cnt-zero blocks (1024 ints each)
#define BCAP 64               // bucket capacity (r14-proven; P(deg>64)~0)

typedef short short8 __attribute__((ext_vector_type(8)));
typedef unsigned short ushort8 __attribute__((ext_vector_type(8)));
typedef float f32x4  __attribute__((ext_vector_type(4)));

__device__ __forceinline__ unsigned short f2bf(float f) {
    unsigned u = __float_as_uint(f);
    u += 0x7FFFu + ((u >> 16) & 1u);      // RNE
    return (unsigned short)(u >> 16);
}
__device__ __forceinline__ float bf_lo(unsigned u) { return __uint_as_float(u << 16); }
__device__ __forceinline__ float bf_hi(unsigned u) { return __uint_as_float(u & 0xFFFF0000u); }

// ===== dispatch 1: gemm tiles + cnt-zero tail (r14/r18-measured-best) =====
// 512 thr = 8 waves x 16 rows; W staged fragment-major in 64KB LDS (fp32->bf16
// inline); B-frag = ds_read_b128 base+lane*16, conflict-free.
// Register-direct epilogue in PERMUTED slot layout: slot s=8*lrow+ct holds
// true col 16*ct+lrow; ushort8 stores are 256B-dense per 16-lane group.
// (r13/r20 lesson: do NOT fuse fill into this dispatch — random-atomic role
// + streaming-MFMA role interfere, 2x slowdown. Keep dispatches role-pure.)
template<bool ZBF>
__global__ __launch_bounds__(512, 4) void gemm_zero_kernel(
    const float* __restrict__ x,
    const float* __restrict__ Wl,
    const float* __restrict__ Wr,
    unsigned short* __restrict__ Yh,      // [NNODES][128] bf16, permuted slots
    unsigned short* __restrict__ Zh,      // [NNODES][128] bf16, permuted (ZBF)
    float* __restrict__ Z,                // = d_out, permuted fp32 (!ZBF)
    int* __restrict__ cnt)
{
    __shared__ unsigned short wfrag[32768];   // 64KB fragment-major W
    const int tid = threadIdx.x;

    if (blockIdx.x >= NTILES) {               // ---- cnt-zero role ----
        int i = (blockIdx.x - NTILES) * 1024 + tid * 2;
        if (i < NNODES) {
            if (i + 1 < NNODES) *(int2*)(cnt + i) = (int2){0, 0};
            else cnt[i] = 0;
        }
        return;
    }

    const int wave = tid >> 6;
    const int lane = tid & 63;
    const int lrow = lane & 15;
    const int kgrp = lane >> 4;
    const int row0 = blockIdx.x * 128 + wave * 16;

    // stage W fragment-major: chunk i=(ct*4+ks)*64+lane = lane's B-frag
#pragma unroll
    for (int it = 0; it < 8; ++it) {
        const int i  = it * 512 + tid;
        const int il = i & 63;
        const int ks = (i >> 6) & 3;
        const int ct = i >> 8;
        const int r  = ct * 16 + (il & 15);
        const int k8 = ks * 4 + (il >> 4);
        const float* wr = ((r < DIM) ? (Wl + (size_t)r * DIM)
                                     : (Wr + (size_t)(r - DIM) * DIM)) + k8 * 8;
        float4 w0 = *(const float4*)(wr);
        float4 w1 = *(const float4*)(wr + 4);
        ushort8 c;
        c[0] = f2bf(w0.x); c[1] = f2bf(w0.y); c[2] = f2bf(w0.z); c[3] = f2bf(w0.w);
        c[4] = f2bf(w1.x); c[5] = f2bf(w1.y); c[6] = f2bf(w1.z); c[7] = f2bf(w1.w);
        *(ushort8*)(wfrag + (size_t)i * 8) = c;
    }
    __syncthreads();

    int arow = row0 + lrow;
    if (arow >= NNODES) arow = NNODES - 1;    // clamped rows never stored
    const float* xrow = x + (size_t)arow * DIM + kgrp * 8;

    f32x4 acc[16];
#pragma unroll
    for (int i = 0; i < 16; ++i) acc[i] = (f32x4){0.f, 0.f, 0.f, 0.f};

#pragma unroll
    for (int ks = 0; ks < 4; ++ks) {
        float4 a0 = *(const float4*)(xrow + ks * 32);
        float4 a1 = *(const float4*)(xrow + ks * 32 + 4);
        short8 af;
        af[0] = (short)f2bf(a0.x); af[1] = (short)f2bf(a0.y);
        af[2] = (short)f2bf(a0.z); af[3] = (short)f2bf(a0.w);
        af[4] = (short)f2bf(a1.x); af[5] = (short)f2bf(a1.y);
        af[6] = (short)f2bf(a1.z); af[7] = (short)f2bf(a1.w);
#pragma unroll
        for (int ct = 0; ct < 16; ++ct) {
            short8 bf = *(const short8*)(wfrag + (size_t)((ct * 4 + ks) * 64 + lane) * 8);
            acc[ct] = __builtin_amdgcn_mfma_f32_16x16x32_bf16(af, bf, acc[ct], 0, 0, 0);
        }
    }

    // ---- register-direct permuted epilogue ----
#pragma unroll
    for (int r = 0; r < 4; ++r) {
        const int row = row0 + kgrp * 4 + r;
        if (row < NNODES) {
            ushort8 y;
#pragma unroll
            for (int ct = 0; ct < 8; ++ct) y[ct] = f2bf(acc[ct][r]);
            *(ushort8*)(Yh + (size_t)row * DIM + lrow * 8) = y;
            if (ZBF) {
                ushort8 zz;
#pragma unroll
                for (int ct = 0; ct < 8; ++ct) zz[ct] = f2bf(acc[ct + 8][r]);
                *(ushort8*)(Zh + (size_t)row * DIM + lrow * 8) = zz;
            } else {
                float4 z0, z1;
                z0.x = acc[8][r];  z0.y = acc[9][r];  z0.z = acc[10][r]; z0.w = acc[11][r];
                z1.x = acc[12][r]; z1.y = acc[13][r]; z1.z = acc[14][r]; z1.w = acc[15][r];
                *(float4*)(Z + (size_t)row * DIM + lrow * 8)     = z0;
                *(float4*)(Z + (size_t)row * DIM + lrow * 8 + 4) = z1;
            }
        }
    }
}

// ===== dispatch 2: bucketed adjacency fill =====
__global__ void fill_kernel(const int* __restrict__ ei,
                            int* __restrict__ cnt, int* __restrict__ adjb) {
    int e = blockIdx.x * 256 + threadIdx.x;
    if (e >= NEDGES) return;
    int src = ei[e];
    int dst = ei[NEDGES + e];
    int p = atomicAdd(&cnt[dst], 1);
    if (p < BCAP) adjb[(size_t)dst * BCAP + p] = src;
}

// ===== dispatch 3: aggregate — r18 form + parallel cnt/bucket issue =====
// one node per 16-lane quarter-wave; lane reads uint4 (8 slots) per row.
// NEW: first 8 bucket slots are loaded IN PARALLEL with cnt[n] (addresses
// independent of deg). Raw entries are VALUE-clamped to [0,NNODES-1] (stale/
// poison slots are safe: poison is negative -> 0; old-replay values are valid
// indices; sum predicated on k<deg so output exact). Removes one dependent
// L2 round trip for the ~81% of nodes with deg<=8. deg>8 continues with the
// proven clamped-index loop.
template<bool ZBF>
__global__ __launch_bounds__(256) void aggregate_kernel(
    const unsigned short* __restrict__ Yh,
    const unsigned short* __restrict__ Zh,
    const int* __restrict__ cnt,
    const int* __restrict__ adjb,
    const float* __restrict__ bias,
    float* __restrict__ out)
{
    const int tid = threadIdx.x;
    const int l16 = tid & 15;
    const int n = blockIdx.x * 16 + (tid >> 4);
    if (n >= NNODES) return;

    const int* bkt = adjb + (size_t)n * BCAP;

    // issue cnt + first-8 bucket slots + Z + bias concurrently (independent)
    int deg_raw = cnt[n];
    int4 braw0 = *(const int4*)(bkt);
    int4 braw1 = *(const int4*)(bkt + 4);

    float bb[8], z[8];
#pragma unroll
    for (int m = 0; m < 8; ++m) bb[m] = bias[16 * m + l16];   // inverse perm
    if (ZBF) {
        uint4 zv = *(const uint4*)(Zh + (size_t)n * DIM + l16 * 8);
        z[0] = bf_lo(zv.x); z[1] = bf_hi(zv.x); z[2] = bf_lo(zv.y); z[3] = bf_hi(zv.y);
        z[4] = bf_lo(zv.z); z[5] = bf_hi(zv.z); z[6] = bf_lo(zv.w); z[7] = bf_hi(zv.w);
    } else {
        float4 z0 = *(const float4*)(out + (size_t)n * DIM + l16 * 8);
        float4 z1 = *(const float4*)(out + (size_t)n * DIM + l16 * 8 + 4);
        z[0] = z0.x; z[1] = z0.y; z[2] = z0.z; z[3] = z0.w;
        z[4] = z1.x; z[5] = z1.y; z[6] = z1.z; z[7] = z1.w;
    }

    int deg = deg_raw;
    if (deg > BCAP) deg = BCAP;

    float a[8];
#pragma unroll
    for (int m = 0; m < 8; ++m) a[m] = 0.f;

    {   // ---- first batch: value-clamped raw slots (no dep on cnt) ----
        int s[8];
        s[0] = braw0.x; s[1] = braw0.y; s[2] = braw0.z; s[3] = braw0.w;
        s[4] = braw1.x; s[5] = braw1.y; s[6] = braw1.z; s[7] = braw1.w;
#pragma unroll
        for (int k = 0; k < 8; ++k) {
            int v = s[k];
            v = (v < 0) ? 0 : v;
            s[k] = (v >= NNODES) ? (NNODES - 1) : v;
        }
        uint4 v[8];
#pragma unroll
        for (int k = 0; k < 8; ++k)
            v[k] = *(const uint4*)(Yh + (size_t)s[k] * DIM + l16 * 8);
#pragma unroll
        for (int k = 0; k < 8; ++k) {
            if (k < deg) {                   // predicated accumulate
                a[0] += bf_lo(v[k].x); a[1] += bf_hi(v[k].x);
                a[2] += bf_lo(v[k].y); a[3] += bf_hi(v[k].y);
                a[4] += bf_lo(v[k].z); a[5] += bf_hi(v[k].z);
                a[6] += bf_lo(v[k].w); a[7] += bf_hi(v[k].w);
            }
        }
    }

    // ---- rare continuation: deg > 8 (clamped-index batches, r14 form) ----
    for (int j = 8; j < deg; j += 8) {
        const int rem = deg - j;
        int s[8];
#pragma unroll
        for (int k = 0; k < 8; ++k) {
            int idx = j + k;
            s[k] = bkt[(idx < deg) ? idx : (deg - 1)];
        }
        uint4 v[8];
#pragma unroll
        for (int k = 0; k < 8; ++k)
            v[k] = *(const uint4*)(Yh + (size_t)s[k] * DIM + l16 * 8);
#pragma unroll
        for (int k = 0; k < 8; ++k) {
            if (k < rem) {
                a[0] += bf_lo(v[k].x); a[1] += bf_hi(v[k].x);
                a[2] += bf_lo(v[k].y); a[3] += bf_hi(v[k].y);
                a[4] += bf_lo(v[k].z); a[5] += bf_hi(v[k].z);
                a[6] += bf_lo(v[k].w); a[7] += bf_hi(v[k].w);
            }
        }
    }

    const float invd = 1.0f / fmaxf((float)deg, 1.0f);
#pragma unroll
    for (int m = 0; m < 8; ++m)              // slot 8*l16+m -> true col 16*m+l16
        out[(size_t)n * DIM + 16 * m + l16] = fmaxf(a[m] * invd + z[m] + bb[m], 0.f);
}

extern "C" void kernel_launch(void* const* d_in, const int* in_sizes, int n_in,
                              void* d_out, int out_size, void* d_ws, size_t ws_size,
                              hipStream_t stream) {
    const float* x  = (const float*)d_in[0];
    const int*   ei = (const int*)d_in[1];   // int32 (harness converts int64)
    const float* Wl = (const float*)d_in[2];
    const float* Wr = (const float*)d_in[3];
    const float* b  = (const float*)d_in[4];
    float* out = (float*)d_out;

    // ws layout:
    //   [0,    400K) cnt   int[NNODES]
    //   [1M,  +25.6M) adjb  int[NNODES*BCAP]
    //   [27M, +25.6M) Yh    bf16[NNODES*128]  (permuted slots)
    //   [53M, +25.6M) Zh    bf16[NNODES*128]  (permuted slots, ZBF only)
    int*            cnt  = (int*)d_ws;
    int*            adjb = (int*)((char*)d_ws + (1ull << 20));
    unsigned short* Yh   = (unsigned short*)((char*)d_ws + (27ull << 20));
    unsigned short* Zh   = (unsigned short*)((char*)d_ws + (53ull << 20));

    const size_t need_zbf = (53ull << 20) + (size_t)NNODES * DIM * 2;  // ~78.6MB
    const bool zbf = (ws_size >= need_zbf);

    if (zbf) {
        gemm_zero_kernel<true><<<NTILES + ZBLK, 512, 0, stream>>>(x, Wl, Wr, Yh, Zh, out, cnt);
        fill_kernel<<<(NEDGES + 255) / 256, 256, 0, stream>>>(ei, cnt, adjb);
        aggregate_kernel<true><<<(NNODES + 15) / 16, 256, 0, stream>>>(Yh, Zh, cnt, adjb, b, out);
    } else {
        gemm_zero_kernel<false><<<NTILES + ZBLK, 512, 0, stream>>>(x, Wl, Wr, Yh, Zh, out, cnt);
        fill_kernel<<<(NEDGES + 255) / 256, 256, 0, stream>>>(ei, cnt, adjb);
        aggregate_kernel<false><<<(NNODES + 15) / 16, 256, 0, stream>>>(Yh, Zh, cnt, adjb, b, out);
    }
}